// Round 5
// baseline (248.753 us; speedup 1.0000x reference)
//
#include <hip/hip_runtime.h>
#include <stdint.h>

// CSSA: B=32, H=W=64, C=64, heads=4, hd=16, strip windows 64x8 -> 256 windows.
// Round 10 RESUBMIT (r4 bench died to infra: "container failed twice").
// Block = (window, HEAD-PAIR). 512 blocks x 1024 thr (16 waves);
// wave w -> head w&1, q-rows (w>>1)*64..+63 (4 tiles == r6 per-thread load).
// LDS: K[512][32ch+pad] 36.9KB + V^T[32][516] 33KB + W 1.2KB = 71.2KB ->
// 2 blocks/CU = 32 waves/CU (r9 traffic win kept, r6 TLP restored).
// Output: block writes ch [32p,32p+32) of every token = ALIGNED 128B: full
// 64B lines from single store instrs, owned by one block -> no RMW churn
// (geometric fix, no L2-timing gamble). Inputs likewise disjoint 128B/block.
// Strides: VSTR=516 (258 dw == 2 mod 32: V-frag read minimal, staging write
// 8-way -> 2-way, epilogue taps minimal); KSTR=36 (18 dw: 9*l15 coprime-16
// -> minimal). launch_bounds(1024,8) caps VGPR 64 for 8 waves/EU (r6-sized
// per-thread state measured VGPR=40 -> no spill expected).
// QK^T transposed (A=K,B=Q) so P's C-layout == K=16 B-frag layout: PV MFMA
// consumes P straight from registers (r6 structure).
#define KSTR 36     // K row: 32 ch + 4 pad shorts (72 B, 8B-aligned frags)
#define VSTR 516    // Vt row: 512 tok + 4 pad shorts (1032 B)

typedef __attribute__((ext_vector_type(4))) short          short4v;
typedef __attribute__((ext_vector_type(4))) float          f32x4;
typedef __attribute__((ext_vector_type(4))) unsigned short us4;
typedef __bf16 bf2_t __attribute__((ext_vector_type(2)));

__device__ __forceinline__ float bf2f(unsigned short u) {
    union { unsigned int i; float f; } x; x.i = ((unsigned int)u) << 16; return x.f;
}
__device__ __forceinline__ unsigned int pk2bf(float lo, float hi) {
#if __has_builtin(__builtin_amdgcn_cvt_pk_bf16_f32)
    union { bf2_t v; unsigned int u; } c;
    c.v = __builtin_amdgcn_cvt_pk_bf16_f32(lo, hi);     // 1 VALU op
    return c.u;
#else
    union { float f; unsigned int u; } a, b; a.f = lo; b.f = hi;
    return __builtin_amdgcn_perm(b.u + 0x8000u, a.u + 0x8000u, 0x07060302u);
#endif
}
__device__ __forceinline__ short4v pk4bf(float a, float b, float c, float d) {
    union { short4v s; unsigned int u[2]; } p;
    p.u[0] = pk2bf(a, b);
    p.u[1] = pk2bf(c, d);
    return p.s;
}

__global__ __launch_bounds__(1024, 8)
void CSSA_69355131896243_kernel(const float* __restrict__ qkv,
                                const float* __restrict__ wconv,
                                const float* __restrict__ bconv,
                                float* __restrict__ out)
{
    __shared__ unsigned short Kl[512 * KSTR];   // 36864 B  K[token][ch] bf16
    __shared__ unsigned short Vt[32 * VSTR];    // 33024 B  V^T[ch][token] bf16
    __shared__ float Wl[288];                   // pair's 32 ch x 9 conv weights
    __shared__ float Bl[32];

    const int tid  = threadIdx.x;
    const int wave = tid >> 6, lane = tid & 63, quad = lane >> 4, l15 = lane & 15;

    // bid = x + 8p + 16y (x=0..7, p=pair, y=0..31): win = x*32+y. Pair-siblings
    // differ by 8 -> same XCD, adjacent dispatch -> concurrent.
    const int bid = blockIdx.x;
    const int p   = (bid >> 3) & 1;
    const int win = (bid & 7) * 32 + (bid >> 4);
    const int b   = win >> 3, wx = win & 7;
    const int pc  = p * 32;                      // pair's first channel

    const size_t ONE  = (size_t)32 * 4096 * 64;
    const size_t base = ((size_t)b * 4096 + (size_t)wx * 8) * 64;
    const float* gQ = qkv + base;
    const float* gK = qkv + ONE + base;
    const float* gV = qkv + 2 * ONE + base;

    // ---- stage pair's K (natural) + V^T as bf16 (32 channels) ----
    {
        const int c8 = tid & 7;          // 4-ch group (0..7) -> ch pc+c8*4..+3
        const int t0 = tid >> 3;         // 128 tokens per round
        #pragma unroll
        for (int r = 0; r < 4; ++r) {
            const int t = r * 128 + t0;
            const size_t goff = (size_t)(t >> 3) * 4096 + (size_t)(t & 7) * 64 + pc + c8 * 4;
            f32x4 kd = *(const f32x4*)(gK + goff);
            f32x4 vd = *(const f32x4*)(gV + goff);
            union { us4 v; unsigned int u[2]; } kb;
            kb.u[0] = pk2bf(kd[0], kd[1]);
            kb.u[1] = pk2bf(kd[2], kd[3]);
            *(us4*)(&Kl[t * KSTR + c8 * 4]) = kb.v;
            const unsigned int v01 = pk2bf(vd[0], vd[1]);
            const unsigned int v23 = pk2bf(vd[2], vd[3]);
            Vt[(c8 * 4 + 0) * VSTR + t] = (unsigned short)(v01 & 0xffffu);
            Vt[(c8 * 4 + 1) * VSTR + t] = (unsigned short)(v01 >> 16);
            Vt[(c8 * 4 + 2) * VSTR + t] = (unsigned short)(v23 & 0xffffu);
            Vt[(c8 * 4 + 3) * VSTR + t] = (unsigned short)(v23 >> 16);
        }
    }
    if (tid < 288) Wl[tid] = wconv[p * 288 + tid];
    if (tid < 32)  Bl[tid] = bconv[pc + tid];

    // ---- Q prefetch + pack (independent of LDS -> overlaps barrier wait) ----
    const float SCL = 0.25f * 1.44269504088896341f;   // scale*log2(e) folded in
    const int hl  = (wave & 1) * 16;     // head offset within pair (LDS rows)
    const int hg  = pc + hl;             // head's first channel (global)
    const int q0  = (wave >> 1) * 64;
    short4v qf[4];   // B[k=d=quad*4+i][n=q=l15]
    #pragma unroll
    for (int t = 0; t < 4; ++t) {
        const int q = q0 + t * 16 + l15;
        f32x4 qv = *(const f32x4*)(gQ + (size_t)(q >> 3) * 4096 + (size_t)(q & 7) * 64 + hg + quad * 4);
        qf[t] = pk4bf(qv[0] * SCL, qv[1] * SCL, qv[2] * SCL, qv[3] * SCL);
    }
    __syncthreads();

    f32x4 acc[4];
    float lp[4];
    #pragma unroll
    for (int t = 0; t < 4; ++t) { acc[t] = (f32x4)0.0f; lp[t] = 0.0f; }

    // ---- main loop: 32 chunks x 16 keys, frags from LDS (imm offsets) ----
    #pragma unroll 4
    for (int c = 0; c < 32; ++c) {
        // K A-frag: A[m=key=l15][k=d=quad*4+i] for this head
        const short4v kf = *(const short4v*)(&Kl[(c * 16 + l15) * KSTR + hl + quad * 4]);
        // V A-frag for PV: A[m=d=l15][k=key=quad*4+i]
        const short4v vf = *(const short4v*)(&Vt[(hl + l15) * VSTR + c * 16 + quad * 4]);
        #pragma unroll
        for (int t = 0; t < 4; ++t) {
            // s^T[key][q]: C row=quad*4+j -> key, col=l15 -> q
            f32x4 s = __builtin_amdgcn_mfma_f32_16x16x16bf16_1k(kf, qf[t], (f32x4)0.0f, 0, 0, 0);
            const float p0 = __builtin_amdgcn_exp2f(s[0]);
            const float p1 = __builtin_amdgcn_exp2f(s[1]);
            const float p2 = __builtin_amdgcn_exp2f(s[2]);
            const float p3 = __builtin_amdgcn_exp2f(s[3]);
            lp[t] += (p0 + p1) + (p2 + p3);
            // P C-layout == K=16 B-frag layout -> PV straight from registers
            acc[t] = __builtin_amdgcn_mfma_f32_16x16x16bf16_1k(vf, pk4bf(p0, p1, p2, p3), acc[t], 0, 0, 0);
        }
    }

    // ---- denominators: cross-quad reduce ----
    float linv[4];
    #pragma unroll
    for (int t = 0; t < 4; ++t) {
        float v = lp[t];
        v += __shfl_xor(v, 16, 64);
        v += __shfl_xor(v, 32, 64);
        linv[t] = __builtin_amdgcn_rcpf(v);
    }

    // ---- epilogue: LePE from resident V^T, normalize, f32x4 stores ----
    #pragma unroll
    for (int j = 0; j < 4; ++j) {
        const int dl = hl + quad * 4 + j;          // LDS channel row
        float w9[9];
        #pragma unroll
        for (int o = 0; o < 9; ++o) w9[o] = Wl[dl * 9 + o];
        const float bs = Bl[dl];
        const unsigned short* vrow = &Vt[dl * VSTR];
        #pragma unroll
        for (int t = 0; t < 4; ++t) {
            const int q = q0 + t * 16 + l15;
            const int y = q >> 3, x = q & 7;
            float lep = bs;
            #pragma unroll
            for (int dy = 0; dy < 3; ++dy) {
                #pragma unroll
                for (int dx = 0; dx < 3; ++dx) {
                    const int yy = y + dy - 1, xx = x + dx - 1;
                    const bool ok = ((unsigned)yy < 64u) && ((unsigned)xx < 8u);
                    const int tt = (q + (dy - 1) * 8 + (dx - 1)) & 511;   // masked if OOB
                    lep += (ok ? w9[dy * 3 + dx] : 0.0f) * bf2f(vrow[tt]);
                }
            }
            acc[t][j] = acc[t][j] * linv[t] + lep;
        }
    }
    float* gO = out + base;
    #pragma unroll
    for (int t = 0; t < 4; ++t) {
        const int q = q0 + t * 16 + l15;
        *(f32x4*)(gO + (size_t)(q >> 3) * 4096 + (size_t)(q & 7) * 64 + hg + quad * 4) = acc[t];
    }
}

extern "C" void kernel_launch(void* const* d_in, const int* in_sizes, int n_in,
                              void* d_out, int out_size, void* d_ws, size_t ws_size,
                              hipStream_t stream) {
    const float* qkv   = (const float*)d_in[0];
    const float* wconv = (const float*)d_in[1];
    const float* bconv = (const float*)d_in[2];
    float* outp = (float*)d_out;
    hipLaunchKernelGGL(CSSA_69355131896243_kernel, dim3(512), dim3(1024), 0, stream,
                       qkv, wconv, bconv, outp);
}

// Round 6
// 214.528 us; speedup vs baseline: 1.1595x; 1.1595x over previous
//
#include <hip/hip_runtime.h>
#include <stdint.h>

// CSSA: B=32, H=W=64, C=64, heads=4, hd=16, strip windows 64x8 -> 256 windows.
// Round 11: r10 structure, ONE fix: launch_bounds(1024,8)->(1024,4).
// r10's forced 8-waves/EU cap squeezed VGPR to 32 -> massive scratch spill
// (WRITE_SIZE 212 MB, FETCH 157 MB, dur 126-205us) — the exact r4/r5
// pathology the r6 comment warned about. With cap 128 the compiler allocates
// naturally (~40-56); HW still reaches 8 waves/EU (needs only VGPR<=64)
// because occupancy is LDS-limited: 71.2KB -> 2 blocks/CU = 32 waves/CU.
// Structure (unchanged from r10): block = (window, HEAD-PAIR), 512 blocks x
// 1024 thr (16 waves); wave w -> head w&1, q-rows (w>>1)*64..+63 (4 tiles).
// Output: block writes ch [32p,32p+32) of every token = ALIGNED 128B: full
// 64B lines owned by one block's single store instr -> no cross-block RMW
// churn (r9 proved the churn: fusing heads cut 183->123.6 MB).
// Strides: VSTR=516 (258 dw == 2 mod 32), KSTR=36 (18 dw, 9*l15 coprime-16).
// QK^T transposed (A=K,B=Q) so P's C-layout == K=16 B-frag layout: PV MFMA
// consumes P straight from registers (r6 structure).
#define KSTR 36     // K row: 32 ch + 4 pad shorts (72 B, 8B-aligned frags)
#define VSTR 516    // Vt row: 512 tok + 4 pad shorts (1032 B)

typedef __attribute__((ext_vector_type(4))) short          short4v;
typedef __attribute__((ext_vector_type(4))) float          f32x4;
typedef __attribute__((ext_vector_type(4))) unsigned short us4;
typedef __bf16 bf2_t __attribute__((ext_vector_type(2)));

__device__ __forceinline__ float bf2f(unsigned short u) {
    union { unsigned int i; float f; } x; x.i = ((unsigned int)u) << 16; return x.f;
}
__device__ __forceinline__ unsigned int pk2bf(float lo, float hi) {
#if __has_builtin(__builtin_amdgcn_cvt_pk_bf16_f32)
    union { bf2_t v; unsigned int u; } c;
    c.v = __builtin_amdgcn_cvt_pk_bf16_f32(lo, hi);     // 1 VALU op
    return c.u;
#else
    union { float f; unsigned int u; } a, b; a.f = lo; b.f = hi;
    return __builtin_amdgcn_perm(b.u + 0x8000u, a.u + 0x8000u, 0x07060302u);
#endif
}
__device__ __forceinline__ short4v pk4bf(float a, float b, float c, float d) {
    union { short4v s; unsigned int u[2]; } p;
    p.u[0] = pk2bf(a, b);
    p.u[1] = pk2bf(c, d);
    return p.s;
}

__global__ __launch_bounds__(1024, 4)
void CSSA_69355131896243_kernel(const float* __restrict__ qkv,
                                const float* __restrict__ wconv,
                                const float* __restrict__ bconv,
                                float* __restrict__ out)
{
    __shared__ unsigned short Kl[512 * KSTR];   // 36864 B  K[token][ch] bf16
    __shared__ unsigned short Vt[32 * VSTR];    // 33024 B  V^T[ch][token] bf16
    __shared__ float Wl[288];                   // pair's 32 ch x 9 conv weights
    __shared__ float Bl[32];

    const int tid  = threadIdx.x;
    const int wave = tid >> 6, lane = tid & 63, quad = lane >> 4, l15 = lane & 15;

    // bid = x + 8p + 16y (x=0..7, p=pair, y=0..31): win = x*32+y. Pair-siblings
    // differ by 8 -> same XCD, adjacent dispatch -> concurrent.
    const int bid = blockIdx.x;
    const int p   = (bid >> 3) & 1;
    const int win = (bid & 7) * 32 + (bid >> 4);
    const int b   = win >> 3, wx = win & 7;
    const int pc  = p * 32;                      // pair's first channel

    const size_t ONE  = (size_t)32 * 4096 * 64;
    const size_t base = ((size_t)b * 4096 + (size_t)wx * 8) * 64;
    const float* gQ = qkv + base;
    const float* gK = qkv + ONE + base;
    const float* gV = qkv + 2 * ONE + base;

    // ---- stage pair's K (natural) + V^T as bf16 (32 channels) ----
    {
        const int c8 = tid & 7;          // 4-ch group (0..7) -> ch pc+c8*4..+3
        const int t0 = tid >> 3;         // 128 tokens per round
        #pragma unroll
        for (int r = 0; r < 4; ++r) {
            const int t = r * 128 + t0;
            const size_t goff = (size_t)(t >> 3) * 4096 + (size_t)(t & 7) * 64 + pc + c8 * 4;
            f32x4 kd = *(const f32x4*)(gK + goff);
            f32x4 vd = *(const f32x4*)(gV + goff);
            union { us4 v; unsigned int u[2]; } kb;
            kb.u[0] = pk2bf(kd[0], kd[1]);
            kb.u[1] = pk2bf(kd[2], kd[3]);
            *(us4*)(&Kl[t * KSTR + c8 * 4]) = kb.v;
            const unsigned int v01 = pk2bf(vd[0], vd[1]);
            const unsigned int v23 = pk2bf(vd[2], vd[3]);
            Vt[(c8 * 4 + 0) * VSTR + t] = (unsigned short)(v01 & 0xffffu);
            Vt[(c8 * 4 + 1) * VSTR + t] = (unsigned short)(v01 >> 16);
            Vt[(c8 * 4 + 2) * VSTR + t] = (unsigned short)(v23 & 0xffffu);
            Vt[(c8 * 4 + 3) * VSTR + t] = (unsigned short)(v23 >> 16);
        }
    }
    if (tid < 288) Wl[tid] = wconv[p * 288 + tid];
    if (tid < 32)  Bl[tid] = bconv[pc + tid];

    // ---- Q prefetch + pack (independent of LDS -> overlaps barrier wait) ----
    const float SCL = 0.25f * 1.44269504088896341f;   // scale*log2(e) folded in
    const int hl  = (wave & 1) * 16;     // head offset within pair (LDS rows)
    const int hg  = pc + hl;             // head's first channel (global)
    const int q0  = (wave >> 1) * 64;
    short4v qf[4];   // B[k=d=quad*4+i][n=q=l15]
    #pragma unroll
    for (int t = 0; t < 4; ++t) {
        const int q = q0 + t * 16 + l15;
        f32x4 qv = *(const f32x4*)(gQ + (size_t)(q >> 3) * 4096 + (size_t)(q & 7) * 64 + hg + quad * 4);
        qf[t] = pk4bf(qv[0] * SCL, qv[1] * SCL, qv[2] * SCL, qv[3] * SCL);
    }
    __syncthreads();

    f32x4 acc[4];
    float lp[4];
    #pragma unroll
    for (int t = 0; t < 4; ++t) { acc[t] = (f32x4)0.0f; lp[t] = 0.0f; }

    // ---- main loop: 32 chunks x 16 keys, frags from LDS (imm offsets) ----
    #pragma unroll 4
    for (int c = 0; c < 32; ++c) {
        // K A-frag: A[m=key=l15][k=d=quad*4+i] for this head
        const short4v kf = *(const short4v*)(&Kl[(c * 16 + l15) * KSTR + hl + quad * 4]);
        // V A-frag for PV: A[m=d=l15][k=key=quad*4+i]
        const short4v vf = *(const short4v*)(&Vt[(hl + l15) * VSTR + c * 16 + quad * 4]);
        #pragma unroll
        for (int t = 0; t < 4; ++t) {
            // s^T[key][q]: C row=quad*4+j -> key, col=l15 -> q
            f32x4 s = __builtin_amdgcn_mfma_f32_16x16x16bf16_1k(kf, qf[t], (f32x4)0.0f, 0, 0, 0);
            const float p0 = __builtin_amdgcn_exp2f(s[0]);
            const float p1 = __builtin_amdgcn_exp2f(s[1]);
            const float p2 = __builtin_amdgcn_exp2f(s[2]);
            const float p3 = __builtin_amdgcn_exp2f(s[3]);
            lp[t] += (p0 + p1) + (p2 + p3);
            // P C-layout == K=16 B-frag layout -> PV straight from registers
            acc[t] = __builtin_amdgcn_mfma_f32_16x16x16bf16_1k(vf, pk4bf(p0, p1, p2, p3), acc[t], 0, 0, 0);
        }
    }

    // ---- denominators: cross-quad reduce ----
    float linv[4];
    #pragma unroll
    for (int t = 0; t < 4; ++t) {
        float v = lp[t];
        v += __shfl_xor(v, 16, 64);
        v += __shfl_xor(v, 32, 64);
        linv[t] = __builtin_amdgcn_rcpf(v);
    }

    // ---- epilogue: LePE from resident V^T, normalize, f32x4 stores ----
    #pragma unroll
    for (int j = 0; j < 4; ++j) {
        const int dl = hl + quad * 4 + j;          // LDS channel row
        float w9[9];
        #pragma unroll
        for (int o = 0; o < 9; ++o) w9[o] = Wl[dl * 9 + o];
        const float bs = Bl[dl];
        const unsigned short* vrow = &Vt[dl * VSTR];
        #pragma unroll
        for (int t = 0; t < 4; ++t) {
            const int q = q0 + t * 16 + l15;
            const int y = q >> 3, x = q & 7;
            float lep = bs;
            #pragma unroll
            for (int dy = 0; dy < 3; ++dy) {
                #pragma unroll
                for (int dx = 0; dx < 3; ++dx) {
                    const int yy = y + dy - 1, xx = x + dx - 1;
                    const bool ok = ((unsigned)yy < 64u) && ((unsigned)xx < 8u);
                    const int tt = (q + (dy - 1) * 8 + (dx - 1)) & 511;   // masked if OOB
                    lep += (ok ? w9[dy * 3 + dx] : 0.0f) * bf2f(vrow[tt]);
                }
            }
            acc[t][j] = acc[t][j] * linv[t] + lep;
        }
    }
    float* gO = out + base;
    #pragma unroll
    for (int t = 0; t < 4; ++t) {
        const int q = q0 + t * 16 + l15;
        *(f32x4*)(gO + (size_t)(q >> 3) * 4096 + (size_t)(q & 7) * 64 + hg + quad * 4) = acc[t];
    }
}

extern "C" void kernel_launch(void* const* d_in, const int* in_sizes, int n_in,
                              void* d_out, int out_size, void* d_ws, size_t ws_size,
                              hipStream_t stream) {
    const float* qkv   = (const float*)d_in[0];
    const float* wconv = (const float*)d_in[1];
    const float* bconv = (const float*)d_in[2];
    float* outp = (float*)d_out;
    hipLaunchKernelGGL(CSSA_69355131896243_kernel, dim3(512), dim3(1024), 0, stream,
                       qkv, wconv, bconv, outp);
}